// Round 1
// baseline (23889.111 us; speedup 1.0000x reference)
//
#include <hip/hip_runtime.h>
#include <hip/hip_bf16.h>
#include <cstddef>

// ---------------- problem constants ----------------
constexpr int HID   = 256;
constexpr int NG    = 7;          // gates: i, f, z, o, ib, fb, d
constexpr int NCOL  = NG * HID;   // 1792 columns of W_cell
constexpr int B     = 512;
constexpr int S     = 512;
constexpr int T     = S - 1;      // 511 steps
constexpr int NT    = 128;        // n_types actually used (randint(0,128))
constexpr int BH    = B * HID;    // 131072

// output layout (flat floats, in reference return order)
constexpr size_t INT_OFF  = 0;                               // intensity (B, T, 128)
constexpr size_t H_OFF    = (size_t)B * T * 128;             // 33488896, h_out (T,B,HID)
constexpr size_t C_OFF    = H_OFF    + (size_t)T * BH;       // c_out  (= c_i, pre-decay)
constexpr size_t CBAR_OFF = C_OFF    + (size_t)T * BH;
constexpr size_t D_OFF    = CBAR_OFF + (size_t)T * BH;
constexpr size_t G_OFF    = D_OFF    + (size_t)T * BH;

__device__ __forceinline__ float sigmoidf(float x) { return 1.0f / (1.0f + __expf(-x)); }
__device__ __forceinline__ float softplusf(float x) {
    // match jax.nn.softplus = log1p(exp(x)), stable
    return (x > 20.0f) ? x : log1pf(expf(x));
}

// ---------------- kernel 1: P[type][n] = emb_table[type] . W_in[:,n] + b_cell[n] ----
// grid (7, 128), block 256. W_in = W_cell rows [0,256)
__global__ __launch_bounds__(256) void precompute_P(
    const float* __restrict__ emb,     // [129][256]
    const float* __restrict__ W_cell,  // [512][1792]
    const float* __restrict__ b_cell,  // [1792]
    float* __restrict__ P)             // [128][1792]
{
    const int n  = blockIdx.x * 256 + threadIdx.x;   // 0..1791
    const int ty = blockIdx.y;                        // 0..127
    __shared__ float e_s[HID];
    e_s[threadIdx.x] = emb[ty * HID + threadIdx.x];
    __syncthreads();
    float acc = b_cell[n];
    #pragma unroll 4
    for (int k = 0; k < HID; ++k)
        acc += e_s[k] * W_cell[(size_t)k * NCOL + n];
    P[(size_t)ty * NCOL + n] = acc;
}

// ---------------- kernel 2: one recurrence step ----------------
// grid 128 blocks (4 batch rows each), block 256 threads (one hidden unit j each)
constexpr int BT = 4;
__global__ __launch_bounds__(256) void step_kernel(
    const float* __restrict__ W_cell,  // [512][1792]; recurrent part = rows [256,512)
    const float* __restrict__ P,       // [128][1792]
    const int*   __restrict__ types,   // [512][512]
    const float* __restrict__ dtime,   // [512][512]
    float* __restrict__ out,           // full output buffer
    float* __restrict__ c_state,       // [512][256] decayed cell carry
    int t)
{
    const int j  = threadIdx.x;         // 0..255
    const int b0 = blockIdx.x * BT;

    __shared__ float h_s[BT][HID];
    if (t > 0) {
        const float* h_prev = out + H_OFF + (size_t)(t - 1) * BH;
        #pragma unroll
        for (int i = 0; i < BT; ++i)
            h_s[i][j] = h_prev[(size_t)(b0 + i) * HID + j];
    } else {
        #pragma unroll
        for (int i = 0; i < BT; ++i) h_s[i][j] = 0.0f;
    }
    __syncthreads();

    // init accumulators from input projection table P
    float acc[NG][BT];
    #pragma unroll
    for (int bb = 0; bb < BT; ++bb) {
        const int ty = types[(size_t)(b0 + bb) * S + t];
        const float* Prow = P + (size_t)ty * NCOL;
        #pragma unroll
        for (int g = 0; g < NG; ++g) acc[g][bb] = Prow[g * HID + j];
    }

    // recurrent GEMM: acc[g][bb] += sum_k h[bb][k] * W_h[k][g*256+j]
    const float* Wh = W_cell + (size_t)HID * NCOL;   // rows 256..511
    #pragma unroll 2
    for (int k = 0; k < HID; ++k) {
        float hv[BT];
        #pragma unroll
        for (int bb = 0; bb < BT; ++bb) hv[bb] = h_s[bb][k];
        const float* wrow = Wh + (size_t)k * NCOL + j;
        #pragma unroll
        for (int g = 0; g < NG; ++g) {
            const float w = wrow[g * HID];
            #pragma unroll
            for (int bb = 0; bb < BT; ++bb) acc[g][bb] += hv[bb] * w;
        }
    }

    // elementwise CT-LSTM update + output writes
    #pragma unroll
    for (int bb = 0; bb < BT; ++bb) {
        const int b = b0 + bb;
        const float i_g   = sigmoidf(acc[0][bb]);
        const float f_g   = sigmoidf(acc[1][bb]);
        const float z_g   = tanhf(acc[2][bb]);
        const float o_g   = sigmoidf(acc[3][bb]);
        const float ib_g  = sigmoidf(acc[4][bb]);
        const float fb_g  = sigmoidf(acc[5][bb]);
        const float delta = softplusf(acc[6][bb]);

        const size_t sj = (size_t)b * HID + j;
        float c_prev, cbar_prev;
        if (t > 0) {
            c_prev    = c_state[sj];
            cbar_prev = out[CBAR_OFF + (size_t)(t - 1) * BH + sj];
        } else {
            c_prev = 0.0f; cbar_prev = 0.0f;
        }

        const float c_i      = f_g * c_prev + i_g * z_g;
        const float cbar_new = fb_g * cbar_prev + ib_g * z_g;
        const float dt       = dtime[(size_t)b * S + (t + 1)];
        const float c_t      = cbar_new + (c_i - cbar_new) * expf(-delta * dt);
        const float h_new    = o_g * tanhf(c_t);

        const size_t o = (size_t)t * BH + sj;
        out[H_OFF    + o] = h_new;
        out[C_OFF    + o] = c_i;
        out[CBAR_OFF + o] = cbar_new;
        out[D_OFF    + o] = delta;
        out[G_OFF    + o] = o_g;
        c_state[sj] = c_t;
    }
}

// ---------------- kernel 3: intensity = softplus(h_out @ W_lam + b_lam) ----------
// grid (ceil(T/16)=32, B), block 128 (one k each), 16 time rows per block
__global__ __launch_bounds__(128) void intensity_kernel(
    const float* __restrict__ out_h,   // = out (reads h_out region)
    const float* __restrict__ W_lam,   // [256][128]
    const float* __restrict__ b_lam,   // [128]
    float* __restrict__ out)
{
    const int k  = threadIdx.x;        // 0..127
    const int b  = blockIdx.y;
    const int t0 = blockIdx.x * 16;
    const int rows = min(16, T - t0);

    __shared__ float hs[16][HID];
    for (int idx = threadIdx.x; idx < rows * HID; idx += 128) {
        const int r = idx >> 8, jj = idx & 255;
        hs[r][jj] = out_h[H_OFF + (size_t)(t0 + r) * BH + (size_t)b * HID + jj];
    }
    __syncthreads();

    float acc[16];
    const float bl = b_lam[k];
    #pragma unroll
    for (int r = 0; r < 16; ++r) acc[r] = bl;

    #pragma unroll 2
    for (int jj = 0; jj < HID; ++jj) {
        const float w = W_lam[(size_t)jj * 128 + k];
        #pragma unroll
        for (int r = 0; r < 16; ++r) acc[r] += hs[r][jj] * w;
    }

    for (int r = 0; r < rows; ++r)
        out[(size_t)b * ((size_t)T * 128) + (size_t)(t0 + r) * 128 + k] = softplusf(acc[r]);
}

// ---------------- launch ----------------
extern "C" void kernel_launch(void* const* d_in, const int* in_sizes, int n_in,
                              void* d_out, int out_size, void* d_ws, size_t ws_size,
                              hipStream_t stream) {
    const int*   types  = (const int*)  d_in[0];
    const float* dtime  = (const float*)d_in[1];
    const float* emb    = (const float*)d_in[2];
    const float* W_cell = (const float*)d_in[3];
    const float* b_cell = (const float*)d_in[4];
    const float* W_lam  = (const float*)d_in[5];
    const float* b_lam  = (const float*)d_in[6];
    float* out = (float*)d_out;

    float* P       = (float*)d_ws;                          // 128*1792*4 = 917504 B
    float* c_state = (float*)((char*)d_ws + (1 << 20));     // 512*256*4  = 524288 B

    precompute_P<<<dim3(NCOL / 256, NT), 256, 0, stream>>>(emb, W_cell, b_cell, P);

    for (int t = 0; t < T; ++t)
        step_kernel<<<B / BT, 256, 0, stream>>>(W_cell, P, types, dtime, out, c_state, t);

    intensity_kernel<<<dim3((T + 15) / 16, B), 128, 0, stream>>>(out, W_lam, b_lam, out);
}